// Round 1
// baseline (132.938 us; speedup 1.0000x reference)
//
#include <hip/hip_runtime.h>
#include <hip/hip_bf16.h>
#include <math.h>

// Problem constants
#define NB 256   // batch
#define NL 256   // sequence length
#define NH 128   // hidden
#define NK 8     // K_MAX

// ---------------------------------------------------------------------------
// Kernel 1: hat[b,l,h] = sum_j e[b,l,j] * W[h,j]   (e @ W^T)
// 64 rows per block, 8x4 micro-tile per thread, K chunked in halves of 64.
// ---------------------------------------------------------------------------
__global__ __launch_bounds__(256) void hat_kernel(const float* __restrict__ e,
                                                  const float* __restrict__ W,
                                                  float* __restrict__ hat) {
    __shared__ __align__(16) float WT[64 * 128];   // WT[kk*128 + (h ^ ((kk&7)<<2))] = W[h][k0+kk]
    __shared__ __align__(16) float eT[64 * 72];    // eT[kk*72 + r] = e[row0+r][k0+kk]
    const int t = threadIdx.x;
    const int rg = t & 7;        // row group: rows rg*8 .. rg*8+7
    const int cg = t >> 3;       // col group: cols cg*4 .. cg*4+3
    const size_t row0 = (size_t)blockIdx.x * 64;

    float acc[8][4];
#pragma unroll
    for (int i = 0; i < 8; ++i)
#pragma unroll
        for (int j = 0; j < 4; ++j) acc[i][j] = 0.f;

    for (int k0 = 0; k0 < 128; k0 += 64) {
        __syncthreads();
        // stage W chunk (transposed + xor swizzle)
        for (int i = t; i < 64 * 128; i += 256) {
            int kk = i & 63, h = i >> 6;
            WT[kk * 128 + (h ^ ((kk & 7) << 2))] = W[h * 128 + k0 + kk];
        }
        // stage e chunk (transposed)
        for (int i = t; i < 64 * 64; i += 256) {
            int kk = i & 63, r = i >> 6;
            eT[kk * 72 + r] = e[(row0 + r) * 128 + k0 + kk];
        }
        __syncthreads();
#pragma unroll 4
        for (int kk = 0; kk < 64; ++kk) {
            const float4 b4 = *(const float4*)&WT[kk * 128 + ((cg * 4) ^ ((kk & 7) << 2))];
            const float4 a0 = *(const float4*)&eT[kk * 72 + rg * 8];
            const float4 a1 = *(const float4*)&eT[kk * 72 + rg * 8 + 4];
            const float a[8] = {a0.x, a0.y, a0.z, a0.w, a1.x, a1.y, a1.z, a1.w};
            const float bb[4] = {b4.x, b4.y, b4.z, b4.w};
#pragma unroll
            for (int i = 0; i < 8; ++i)
#pragma unroll
                for (int j = 0; j < 4; ++j) acc[i][j] += a[i] * bb[j];
        }
    }
#pragma unroll
    for (int i = 0; i < 8; ++i) {
        size_t row = row0 + rg * 8 + i;
        float4 r;
        r.x = acc[i][0]; r.y = acc[i][1]; r.z = acc[i][2]; r.w = acc[i][3];
        *(float4*)&hat[row * 128 + cg * 4] = r;
    }
}

// ---------------------------------------------------------------------------
// Kernel 2: dynamic routing. One block per batch b. 256 threads (4 waves).
// Produces final c (softmax of routed logits) and capsule strengths.
// ---------------------------------------------------------------------------
__global__ __launch_bounds__(256) void routing_kernel(const float* __restrict__ hat,
                                                      const float* __restrict__ b_init,
                                                      float* __restrict__ c_out,
                                                      float* __restrict__ str_out) {
    const int b = blockIdx.x;
    const int t = threadIdx.x;
    const int lane = t & 63, wv = t >> 6;
    __shared__ float logits[NK * NL];
    __shared__ float c[NK * NL];
    __shared__ __align__(16) float tile[64 * 129];
    __shared__ float cap[NK * NH];
    __shared__ float red[2048];
    __shared__ float nrm[NK];
    const float* hatb = hat + (size_t)b * (NL * NH);

    for (int i = t; i < NK * NL; i += 256) logits[i] = b_init[(size_t)b * (NK * NL) + i];
    __syncthreads();

    const int h = t & 127, half = t >> 7;
    const int lsub = t & 63, q = t >> 6;

    for (int iter = 0; iter < 3; ++iter) {
        // --- softmax over L per capsule; wave wv handles rows 2wv, 2wv+1 ---
        for (int rr = 0; rr < 2; ++rr) {
            const int k = wv * 2 + rr;
            float v0 = logits[k * 256 + lane];
            float v1 = logits[k * 256 + 64 + lane];
            float v2 = logits[k * 256 + 128 + lane];
            float v3 = logits[k * 256 + 192 + lane];
            float m = fmaxf(fmaxf(v0, v1), fmaxf(v2, v3));
            for (int off = 32; off; off >>= 1) m = fmaxf(m, __shfl_xor(m, off));
            v0 = expf(v0 - m); v1 = expf(v1 - m); v2 = expf(v2 - m); v3 = expf(v3 - m);
            float s = v0 + v1 + v2 + v3;
            for (int off = 32; off; off >>= 1) s += __shfl_xor(s, off);
            const float inv = 1.0f / s;
            c[k * 256 + lane] = v0 * inv;
            c[k * 256 + 64 + lane] = v1 * inv;
            c[k * 256 + 128 + lane] = v2 * inv;
            c[k * 256 + 192 + lane] = v3 * inv;
        }
        __syncthreads();

        // --- cap[k][h] = sum_l c[k][l] * hat[l][h] ---
        float acc[8] = {0, 0, 0, 0, 0, 0, 0, 0};
        for (int l0 = 0; l0 < 256; l0 += 64) {
            for (int i = t; i < 64 * 128; i += 256)
                tile[(i >> 7) * 129 + (i & 127)] = hatb[(size_t)l0 * 128 + i];
            __syncthreads();
            for (int li = half; li < 64; li += 2) {
                const float v = tile[li * 129 + h];
                const float* cl = &c[l0 + li];
#pragma unroll
                for (int k = 0; k < 8; ++k) acc[k] += cl[k * 256] * v;
            }
            __syncthreads();
        }
#pragma unroll
        for (int k = 0; k < 8; ++k) red[(half * 8 + k) * 128 + h] = acc[k];
        __syncthreads();
        for (int i = t; i < 1024; i += 256) cap[i] = red[i] + red[1024 + i];
        __syncthreads();

        // --- squared norms + squash scale ---
        for (int rr = 0; rr < 2; ++rr) {
            const int k = wv * 2 + rr;
            float x0 = cap[k * 128 + lane], x1 = cap[k * 128 + 64 + lane];
            float s = x0 * x0 + x1 * x1;
            for (int off = 32; off; off >>= 1) s += __shfl_xor(s, off);
            if (lane == 0) nrm[k] = s;
        }
        __syncthreads();
        for (int i = t; i < 1024; i += 256) {
            const float n = nrm[i >> 7];
            cap[i] *= n / (1.0f + n) / sqrtf(n + 1e-9f);
        }
        __syncthreads();

        // --- delta[k][l] = sum_h hat[l][h] * cap[k][h]; logits += delta ---
        if (iter < 2) {
            for (int l0 = 0; l0 < 256; l0 += 64) {
                for (int i = t; i < 64 * 128; i += 256)
                    tile[(i >> 7) * 129 + (i & 127)] = hatb[(size_t)l0 * 128 + i];
                __syncthreads();
                float p[8] = {0, 0, 0, 0, 0, 0, 0, 0};
                for (int hh = q * 32; hh < q * 32 + 32; ++hh) {
                    const float v = tile[lsub * 129 + hh];
#pragma unroll
                    for (int k = 0; k < 8; ++k) p[k] += v * cap[k * 128 + hh];
                }
#pragma unroll
                for (int k = 0; k < 8; ++k) red[(q * 8 + k) * 64 + lsub] = p[k];
                __syncthreads();
                for (int pid = t; pid < 512; pid += 256) {
                    const int kk = pid >> 6, ll = pid & 63;
                    const float d = red[kk * 64 + ll] + red[(8 + kk) * 64 + ll] +
                                    red[(16 + kk) * 64 + ll] + red[(24 + kk) * 64 + ll];
                    logits[kk * 256 + l0 + ll] += d;
                }
                __syncthreads();
            }
        }
    }

    // --- strengths of final scaled capsules ---
    for (int rr = 0; rr < 2; ++rr) {
        const int k = wv * 2 + rr;
        float x0 = cap[k * 128 + lane], x1 = cap[k * 128 + 64 + lane];
        float s = x0 * x0 + x1 * x1;
        for (int off = 32; off; off >>= 1) s += __shfl_xor(s, off);
        if (lane == 0) str_out[b * 8 + k] = sqrtf(s);
    }
    for (int i = t; i < NK * NL; i += 256) c_out[(size_t)b * (NK * NL) + i] = c[i];
}

// ---------------------------------------------------------------------------
// Kernel 3: per-batch scoring. mu per capsule, s[k]=sum_l c*cos, Gram P,
// then sorted prefix scan over k=2..8 and argmax.
// ---------------------------------------------------------------------------
__global__ __launch_bounds__(256) void score_kernel(const float* __restrict__ e_in,
                                                    const float* __restrict__ c_in,
                                                    const float* __restrict__ str_in,
                                                    float* __restrict__ out) {
    const int b = blockIdx.x;
    const int t = threadIdx.x;
    const int lane = t & 63, wv = t >> 6;
    __shared__ float c[NK * NL];
    __shared__ __align__(16) float tile[64 * 129];
    __shared__ float mu[NK * NH];
    __shared__ float red[2048];
    __shared__ float en2red[256];
    __shared__ float enl[64];
    __shared__ float denom[NK], nrmv[NK], svals[NK], Ps[28], str[NK];
    const float* eb = e_in + (size_t)b * (NL * NH);

    for (int i = t; i < NK * NL; i += 256) c[i] = c_in[(size_t)b * (NK * NL) + i];
    if (t < 8) str[t] = str_in[b * 8 + t];
    __syncthreads();

    // denom[k] = sum_l c[k][l] + eps8
    for (int rr = 0; rr < 2; ++rr) {
        const int k = wv * 2 + rr;
        float s = c[k * 256 + lane] + c[k * 256 + 64 + lane] +
                  c[k * 256 + 128 + lane] + c[k * 256 + 192 + lane];
        for (int off = 32; off; off >>= 1) s += __shfl_xor(s, off);
        if (lane == 0) denom[k] = s + 1e-8f;
    }
    __syncthreads();

    const int h = t & 127, half = t >> 7;
    // --- pass A: mu[k][h] = (sum_l c[k][l]*e[l][h]) / denom[k], then normalize ---
    float acc[8] = {0, 0, 0, 0, 0, 0, 0, 0};
    for (int l0 = 0; l0 < 256; l0 += 64) {
        for (int i = t; i < 64 * 128; i += 256)
            tile[(i >> 7) * 129 + (i & 127)] = eb[(size_t)l0 * 128 + i];
        __syncthreads();
        for (int li = half; li < 64; li += 2) {
            const float v = tile[li * 129 + h];
            const float* cl = &c[l0 + li];
#pragma unroll
            for (int k = 0; k < 8; ++k) acc[k] += cl[k * 256] * v;
        }
        __syncthreads();
    }
#pragma unroll
    for (int k = 0; k < 8; ++k) red[(half * 8 + k) * 128 + h] = acc[k];
    __syncthreads();
    for (int i = t; i < 1024; i += 256) mu[i] = (red[i] + red[1024 + i]) / denom[i >> 7];
    __syncthreads();
    for (int rr = 0; rr < 2; ++rr) {
        const int k = wv * 2 + rr;
        float x0 = mu[k * 128 + lane], x1 = mu[k * 128 + 64 + lane];
        float s = x0 * x0 + x1 * x1;
        for (int off = 32; off; off >>= 1) s += __shfl_xor(s, off);
        if (lane == 0) nrmv[k] = sqrtf(s) + 1e-8f;
    }
    __syncthreads();
    for (int i = t; i < 1024; i += 256) mu[i] /= nrmv[i >> 7];  // now mu_n
    __syncthreads();

    // --- pass B: s[k] = sum_l c[k][l] * cos(e_l, mu_n_k) ---
    const int lsub = t & 63, q = t >> 6;
    float slo = 0.f, shi = 0.f;
    for (int l0 = 0; l0 < 256; l0 += 64) {
        for (int i = t; i < 64 * 128; i += 256)
            tile[(i >> 7) * 129 + (i & 127)] = eb[(size_t)l0 * 128 + i];
        __syncthreads();
        float p[8] = {0, 0, 0, 0, 0, 0, 0, 0};
        float en2 = 0.f;
        for (int hh = q * 32; hh < q * 32 + 32; ++hh) {
            const float v = tile[lsub * 129 + hh];
            en2 += v * v;
#pragma unroll
            for (int k = 0; k < 8; ++k) p[k] += v * mu[k * 128 + hh];
        }
#pragma unroll
        for (int k = 0; k < 8; ++k) red[(q * 8 + k) * 64 + lsub] = p[k];
        en2red[q * 64 + lsub] = en2;
        __syncthreads();
        if (t < 64)
            enl[t] = sqrtf(en2red[t] + en2red[64 + t] + en2red[128 + t] + en2red[192 + t]) + 1e-8f;
        __syncthreads();
        {
            const int k2 = q + 4;
            const float d0 = red[(0 * 8 + q) * 64 + lsub] + red[(1 * 8 + q) * 64 + lsub] +
                             red[(2 * 8 + q) * 64 + lsub] + red[(3 * 8 + q) * 64 + lsub];
            const float d1 = red[(0 * 8 + k2) * 64 + lsub] + red[(1 * 8 + k2) * 64 + lsub] +
                             red[(2 * 8 + k2) * 64 + lsub] + red[(3 * 8 + k2) * 64 + lsub];
            const float el = enl[lsub];
            slo += c[q * 256 + l0 + lsub] * (d0 / el);
            shi += c[k2 * 256 + l0 + lsub] * (d1 / el);
        }
        __syncthreads();
    }
    for (int off = 32; off; off >>= 1) {
        slo += __shfl_xor(slo, off);
        shi += __shfl_xor(shi, off);
    }
    if (lane == 0) { svals[wv] = slo; svals[wv + 4] = shi; }
    __syncthreads();

    // --- Gram matrix pairs P[i<j] = mu_n_i . mu_n_j ---
    for (int p = wv; p < 28; p += 4) {
        int i = 0, rem = p;
        while (rem >= 7 - i) { rem -= 7 - i; ++i; }
        const int j = i + 1 + rem;
        float v = mu[i * 128 + lane] * mu[j * 128 + lane] +
                  mu[i * 128 + 64 + lane] * mu[j * 128 + 64 + lane];
        for (int off = 32; off; off >>= 1) v += __shfl_xor(v, off);
        if (lane == 0) Ps[p] = v;
    }
    __syncthreads();

    // --- serial scoring on thread 0 ---
    if (t == 0) {
        int idx[8];
        for (int i = 0; i < 8; ++i) idx[i] = i;
        for (int a = 1; a < 8; ++a) {           // stable insertion sort, descending
            const int key = idx[a];
            const float kv = str[key];
            int bb = a - 1;
            while (bb >= 0 && str[idx[bb]] < kv) { idx[bb + 1] = idx[bb]; --bb; }
            idx[bb + 1] = key;
        }
        float best = -1e30f;
        int bestk = 2;
        float cons_sum = 0.f, pair_sum = 0.f;
        for (int kk = 1; kk <= 8; ++kk) {
            const int ni = idx[kk - 1];
            cons_sum += svals[ni];
            for (int a = 0; a < kk - 1; ++a) {
                const int ia = idx[a];
                const int lo = ia < ni ? ia : ni;
                const int hi2 = ia < ni ? ni : ia;
                const int off0 = lo * 7 - lo * (lo - 1) / 2;
                pair_sum += Ps[off0 + hi2 - lo - 1];
            }
            if (kk >= 2) {
                const float cons = cons_sum / (kk * 256.0f);
                const float divv = 1.0f - (2.0f / (kk * (kk - 1))) * pair_sum;
                const float score = 0.5f * cons + 0.5f * divv;
                out[256 + b * 7 + (kk - 2)] = score;
                if (score > best) { best = score; bestk = kk; }
            }
        }
        out[b] = (float)bestk;
    }
}

// ---------------------------------------------------------------------------
extern "C" void kernel_launch(void* const* d_in, const int* in_sizes, int n_in,
                              void* d_out, int out_size, void* d_ws, size_t ws_size,
                              hipStream_t stream) {
    const float* e = (const float*)d_in[0];       // [256,256,128]
    const float* W = (const float*)d_in[1];       // [128,128]
    const float* b_init = (const float*)d_in[2];  // [256,8,256]
    float* out = (float*)d_out;                   // 256 + 256*7 floats

    float* hat = (float*)d_ws;                                // [256,256,128]
    float* c_final = hat + (size_t)NB * NL * NH;              // [256,8,256]
    float* strength = c_final + (size_t)NB * NK * NL;         // [256,8]

    hipLaunchKernelGGL(hat_kernel, dim3((NB * NL) / 64), dim3(256), 0, stream, e, W, hat);
    hipLaunchKernelGGL(routing_kernel, dim3(NB), dim3(256), 0, stream, hat, b_init, c_final, strength);
    hipLaunchKernelGGL(score_kernel, dim3(NB), dim3(256), 0, stream, e, c_final, strength, out);
}

// Round 2
// 92.498 us; speedup vs baseline: 1.4372x; 1.4372x over previous
//
#include <hip/hip_runtime.h>
#include <hip/hip_bf16.h>
#include <math.h>

#define NB 256   // batch
#define NL 256   // sequence length
#define NH 128   // hidden
#define NK 8     // K_MAX

// ---------------------------------------------------------------------------
// Kernel 1: hat[b,l,h] = sum_j e[b,l,j] * W[h,j]   (e @ W^T)
// ---------------------------------------------------------------------------
__global__ __launch_bounds__(256) void hat_kernel(const float* __restrict__ e,
                                                  const float* __restrict__ W,
                                                  float* __restrict__ hat) {
    __shared__ __align__(16) float WT[64 * 128];
    __shared__ __align__(16) float eT[64 * 72];
    const int t = threadIdx.x;
    const int rg = t & 7;
    const int cg = t >> 3;
    const size_t row0 = (size_t)blockIdx.x * 64;

    float acc[8][4];
#pragma unroll
    for (int i = 0; i < 8; ++i)
#pragma unroll
        for (int j = 0; j < 4; ++j) acc[i][j] = 0.f;

    for (int k0 = 0; k0 < 128; k0 += 64) {
        __syncthreads();
        for (int i = t; i < 64 * 128; i += 256) {
            int kk = i & 63, h = i >> 6;
            WT[kk * 128 + (h ^ ((kk & 7) << 2))] = W[h * 128 + k0 + kk];
        }
        for (int i = t; i < 64 * 64; i += 256) {
            int kk = i & 63, r = i >> 6;
            eT[kk * 72 + r] = e[(row0 + r) * 128 + k0 + kk];
        }
        __syncthreads();
#pragma unroll 4
        for (int kk = 0; kk < 64; ++kk) {
            const float4 b4 = *(const float4*)&WT[kk * 128 + ((cg * 4) ^ ((kk & 7) << 2))];
            const float4 a0 = *(const float4*)&eT[kk * 72 + rg * 8];
            const float4 a1 = *(const float4*)&eT[kk * 72 + rg * 8 + 4];
            const float a[8] = {a0.x, a0.y, a0.z, a0.w, a1.x, a1.y, a1.z, a1.w};
            const float bb[4] = {b4.x, b4.y, b4.z, b4.w};
#pragma unroll
            for (int i = 0; i < 8; ++i)
#pragma unroll
                for (int j = 0; j < 4; ++j) acc[i][j] += a[i] * bb[j];
        }
    }
#pragma unroll
    for (int i = 0; i < 8; ++i) {
        size_t row = row0 + rg * 8 + i;
        float4 r;
        r.x = acc[i][0]; r.y = acc[i][1]; r.z = acc[i][2]; r.w = acc[i][3];
        *(float4*)&hat[row * 128 + cg * 4] = r;
    }
}

// ---------------------------------------------------------------------------
// Kernel 2: dynamic routing. One block per batch, 1024 threads (16 waves).
// ---------------------------------------------------------------------------
__global__ __launch_bounds__(1024) void routing_kernel(const float* __restrict__ hat,
                                                       const float* __restrict__ b_init,
                                                       float* __restrict__ c_out,
                                                       float* __restrict__ str_out) {
    const int b = blockIdx.x;
    const int t = threadIdx.x;
    const int lane = t & 63, wv = t >> 6;
    __shared__ float logits[NK * NL];              // 8 KB
    __shared__ __align__(16) float ct[NL * 12];    // c transposed [l][k], 12 KB
    __shared__ __align__(16) float cap[NK * NH];   // 4 KB
    __shared__ __align__(16) float red[8192];      // 32 KB
    __shared__ __align__(16) float tile[64 * 129]; // 33 KB
    __shared__ float nrm[NK];
    const float* hatb = hat + (size_t)b * (NL * NH);

    logits[t] = b_init[(size_t)b * 2048 + t];
    logits[t + 1024] = b_init[(size_t)b * 2048 + t + 1024];
    __syncthreads();

    const int h = t & 127, lgrp = t >> 7;

    for (int iter = 0; iter < 3; ++iter) {
        // --- softmax over L, one wave per capsule row ---
        if (wv < 8) {
            const int k = wv;
            float v0 = logits[k * 256 + lane];
            float v1 = logits[k * 256 + 64 + lane];
            float v2 = logits[k * 256 + 128 + lane];
            float v3 = logits[k * 256 + 192 + lane];
            float m = fmaxf(fmaxf(v0, v1), fmaxf(v2, v3));
            for (int o = 32; o; o >>= 1) m = fmaxf(m, __shfl_xor(m, o));
            v0 = expf(v0 - m); v1 = expf(v1 - m); v2 = expf(v2 - m); v3 = expf(v3 - m);
            float s = v0 + v1 + v2 + v3;
            for (int o = 32; o; o >>= 1) s += __shfl_xor(s, o);
            const float inv = 1.0f / s;
            ct[lane * 12 + k] = v0 * inv;
            ct[(lane + 64) * 12 + k] = v1 * inv;
            ct[(lane + 128) * 12 + k] = v2 * inv;
            ct[(lane + 192) * 12 + k] = v3 * inv;
        }
        __syncthreads();

        // --- cap_raw[k][h] = sum_l ct[l][k] * hat[l][h]  (global-direct reads) ---
        float acc[8] = {0, 0, 0, 0, 0, 0, 0, 0};
        {
            const int l0g = lgrp * 32;
#pragma unroll 4
            for (int li = 0; li < 32; ++li) {
                const int l = l0g + li;
                const float ev = hatb[l * 128 + h];
                const float4 c0 = *(const float4*)&ct[l * 12];
                const float4 c1 = *(const float4*)&ct[l * 12 + 4];
                acc[0] += c0.x * ev; acc[1] += c0.y * ev; acc[2] += c0.z * ev; acc[3] += c0.w * ev;
                acc[4] += c1.x * ev; acc[5] += c1.y * ev; acc[6] += c1.z * ev; acc[7] += c1.w * ev;
            }
        }
#pragma unroll
        for (int k = 0; k < 8; ++k) red[lgrp * 1024 + k * 128 + h] = acc[k];
        __syncthreads();
        {
            float cv = 0.f;
#pragma unroll
            for (int g = 0; g < 8; ++g) cv += red[g * 1024 + t];
            cap[t] = cv;
        }
        __syncthreads();
        if (wv < 8) {
            const int k = wv;
            float x0 = cap[k * 128 + lane], x1 = cap[k * 128 + 64 + lane];
            float s = x0 * x0 + x1 * x1;
            for (int o = 32; o; o >>= 1) s += __shfl_xor(s, o);
            if (lane == 0) nrm[k] = s;
        }
        __syncthreads();
        {
            const float n = nrm[t >> 7];
            cap[t] = cap[t] * (n / (1.0f + n) / sqrtf(n + 1e-9f));
        }
        __syncthreads();

        // --- delta[k][l] = sum_h hat[l][h]*cap[k][h]; logits += delta ---
        if (iter < 2) {
            for (int l0 = 0; l0 < 256; l0 += 64) {
#pragma unroll
                for (int rep = 0; rep < 2; ++rep) {
                    const int i2 = t + rep * 1024;
                    const int r = i2 >> 5, c0 = (i2 & 31) * 4;
                    const float4 v = *(const float4*)&hatb[(size_t)(l0 + r) * 128 + c0];
                    tile[r * 129 + c0 + 0] = v.x;
                    tile[r * 129 + c0 + 1] = v.y;
                    tile[r * 129 + c0 + 2] = v.z;
                    tile[r * 129 + c0 + 3] = v.w;
                }
                __syncthreads();
                const int h0 = wv * 8;
                float cr[8][8];
#pragma unroll
                for (int k = 0; k < 8; ++k) {
                    const float4 a = *(const float4*)&cap[k * 128 + h0];
                    const float4 bq = *(const float4*)&cap[k * 128 + h0 + 4];
                    cr[k][0] = a.x; cr[k][1] = a.y; cr[k][2] = a.z; cr[k][3] = a.w;
                    cr[k][4] = bq.x; cr[k][5] = bq.y; cr[k][6] = bq.z; cr[k][7] = bq.w;
                }
                float p[8] = {0, 0, 0, 0, 0, 0, 0, 0};
#pragma unroll
                for (int u = 0; u < 8; ++u) {
                    const float v = tile[lane * 129 + h0 + u];
#pragma unroll
                    for (int k = 0; k < 8; ++k) p[k] += v * cr[k][u];
                }
#pragma unroll
                for (int k = 0; k < 8; ++k) red[wv * 512 + k * 64 + lane] = p[k];
                __syncthreads();
                if (t < 512) {
                    float d = 0.f;
#pragma unroll
                    for (int q = 0; q < 16; ++q) d += red[q * 512 + t];
                    logits[(t >> 6) * 256 + l0 + (t & 63)] += d;
                }
                __syncthreads();
            }
        }
    }

    // --- strengths + c export ---
    if (wv < 8) {
        const int k = wv;
        float x0 = cap[k * 128 + lane], x1 = cap[k * 128 + 64 + lane];
        float s = x0 * x0 + x1 * x1;
        for (int o = 32; o; o >>= 1) s += __shfl_xor(s, o);
        if (lane == 0) str_out[b * 8 + k] = sqrtf(s);
    }
#pragma unroll
    for (int rep = 0; rep < 2; ++rep) {
        const int i = t + rep * 1024;
        c_out[(size_t)b * 2048 + i] = ct[(i & 255) * 12 + (i >> 8)];
    }
}

// ---------------------------------------------------------------------------
// Kernel 3: per-batch scoring, 1024 threads.
// ---------------------------------------------------------------------------
__global__ __launch_bounds__(1024) void score_kernel(const float* __restrict__ e_in,
                                                     const float* __restrict__ c_in,
                                                     const float* __restrict__ str_in,
                                                     float* __restrict__ out) {
    const int b = blockIdx.x;
    const int t = threadIdx.x;
    const int lane = t & 63, wv = t >> 6;
    __shared__ __align__(16) float ct[NL * 12];     // 12 KB
    __shared__ __align__(16) float tile[64 * 129];  // 33 KB
    __shared__ __align__(16) float mu[NK * NH];     // 4 KB
    __shared__ __align__(16) float red[16 * 576];   // 36.9 KB
    __shared__ float enl[64];
    __shared__ float denom[NK], nrmv[NK], svals[NK], Ps[28], str[NK];
    const float* eb = e_in + (size_t)b * (NL * NH);

#pragma unroll
    for (int rep = 0; rep < 2; ++rep) {
        const int i = t + rep * 1024;
        ct[(i & 255) * 12 + (i >> 8)] = c_in[(size_t)b * 2048 + i];
    }
    if (t < 8) str[t] = str_in[b * 8 + t];
    __syncthreads();

    if (wv < 8) {
        const int k = wv;
        float s = ct[lane * 12 + k] + ct[(lane + 64) * 12 + k] +
                  ct[(lane + 128) * 12 + k] + ct[(lane + 192) * 12 + k];
        for (int o = 32; o; o >>= 1) s += __shfl_xor(s, o);
        if (lane == 0) denom[k] = s + 1e-8f;
    }
    __syncthreads();

    const int h = t & 127, lgrp = t >> 7;

    // --- pass A: mu (global-direct) ---
    {
        float acc[8] = {0, 0, 0, 0, 0, 0, 0, 0};
        const int l0g = lgrp * 32;
#pragma unroll 4
        for (int li = 0; li < 32; ++li) {
            const int l = l0g + li;
            const float ev = eb[l * 128 + h];
            const float4 c0 = *(const float4*)&ct[l * 12];
            const float4 c1 = *(const float4*)&ct[l * 12 + 4];
            acc[0] += c0.x * ev; acc[1] += c0.y * ev; acc[2] += c0.z * ev; acc[3] += c0.w * ev;
            acc[4] += c1.x * ev; acc[5] += c1.y * ev; acc[6] += c1.z * ev; acc[7] += c1.w * ev;
        }
#pragma unroll
        for (int k = 0; k < 8; ++k) red[lgrp * 1024 + k * 128 + h] = acc[k];
    }
    __syncthreads();
    {
        float cv = 0.f;
#pragma unroll
        for (int g = 0; g < 8; ++g) cv += red[g * 1024 + t];
        mu[t] = cv / denom[t >> 7];
    }
    __syncthreads();
    if (wv < 8) {
        const int k = wv;
        float x0 = mu[k * 128 + lane], x1 = mu[k * 128 + 64 + lane];
        float s = x0 * x0 + x1 * x1;
        for (int o = 32; o; o >>= 1) s += __shfl_xor(s, o);
        if (lane == 0) nrmv[k] = sqrtf(s) + 1e-8f;
    }
    __syncthreads();
    mu[t] /= nrmv[t >> 7];
    __syncthreads();

    // --- pass B: s[k] = sum_l c[k][l] * cos(e_l, mu_n_k) ---
    float mr[8][8];
    {
        const int h0 = wv * 8;
#pragma unroll
        for (int k = 0; k < 8; ++k) {
            const float4 a = *(const float4*)&mu[k * 128 + h0];
            const float4 bq = *(const float4*)&mu[k * 128 + h0 + 4];
            mr[k][0] = a.x; mr[k][1] = a.y; mr[k][2] = a.z; mr[k][3] = a.w;
            mr[k][4] = bq.x; mr[k][5] = bq.y; mr[k][6] = bq.z; mr[k][7] = bq.w;
        }
    }
    float sacc = 0.f;
    for (int l0 = 0; l0 < 256; l0 += 64) {
#pragma unroll
        for (int rep = 0; rep < 2; ++rep) {
            const int i2 = t + rep * 1024;
            const int r = i2 >> 5, c0 = (i2 & 31) * 4;
            const float4 v = *(const float4*)&eb[(size_t)(l0 + r) * 128 + c0];
            tile[r * 129 + c0 + 0] = v.x;
            tile[r * 129 + c0 + 1] = v.y;
            tile[r * 129 + c0 + 2] = v.z;
            tile[r * 129 + c0 + 3] = v.w;
        }
        __syncthreads();
        {
            const int h0 = wv * 8;
            float en2 = 0.f;
            float p[8] = {0, 0, 0, 0, 0, 0, 0, 0};
#pragma unroll
            for (int u = 0; u < 8; ++u) {
                const float v = tile[lane * 129 + h0 + u];
                en2 += v * v;
#pragma unroll
                for (int k = 0; k < 8; ++k) p[k] += v * mr[k][u];
            }
#pragma unroll
            for (int k = 0; k < 8; ++k) red[wv * 576 + k * 64 + lane] = p[k];
            red[wv * 576 + 512 + lane] = en2;
        }
        __syncthreads();
        if (t < 64) {
            float s2 = 0.f;
#pragma unroll
            for (int q = 0; q < 16; ++q) s2 += red[q * 576 + 512 + t];
            enl[t] = sqrtf(s2) + 1e-8f;
        }
        __syncthreads();
        if (t < 512) {
            const int k = t >> 6, l = t & 63;
            float d = 0.f;
#pragma unroll
            for (int q = 0; q < 16; ++q) d += red[q * 576 + t];
            float val = ct[(l0 + l) * 12 + k] * (d / enl[l]);
            for (int o = 32; o; o >>= 1) val += __shfl_xor(val, o);
            sacc += val;
        }
        __syncthreads();
    }
    if (wv < 8 && lane == 0) svals[wv] = sacc;
    __syncthreads();

    // --- Gram pairs ---
    for (int p = wv; p < 28; p += 16) {
        int i = 0, rem = p;
        while (rem >= 7 - i) { rem -= 7 - i; ++i; }
        const int j = i + 1 + rem;
        float v = mu[i * 128 + lane] * mu[j * 128 + lane] +
                  mu[i * 128 + 64 + lane] * mu[j * 128 + 64 + lane];
        for (int o = 32; o; o >>= 1) v += __shfl_xor(v, o);
        if (lane == 0) Ps[p] = v;
    }
    __syncthreads();

    if (t == 0) {
        int idx[8];
        for (int i = 0; i < 8; ++i) idx[i] = i;
        for (int a = 1; a < 8; ++a) {
            const int key = idx[a];
            const float kv = str[key];
            int bb = a - 1;
            while (bb >= 0 && str[idx[bb]] < kv) { idx[bb + 1] = idx[bb]; --bb; }
            idx[bb + 1] = key;
        }
        float best = -1e30f;
        int bestk = 2;
        float cons_sum = 0.f, pair_sum = 0.f;
        for (int kk = 1; kk <= 8; ++kk) {
            const int ni = idx[kk - 1];
            cons_sum += svals[ni];
            for (int a = 0; a < kk - 1; ++a) {
                const int ia = idx[a];
                const int lo = ia < ni ? ia : ni;
                const int hi2 = ia < ni ? ni : ia;
                const int off0 = lo * 7 - lo * (lo - 1) / 2;
                pair_sum += Ps[off0 + hi2 - lo - 1];
            }
            if (kk >= 2) {
                const float cons = cons_sum / (kk * 256.0f);
                const float divv = 1.0f - (2.0f / (kk * (kk - 1))) * pair_sum;
                const float score = 0.5f * cons + 0.5f * divv;
                out[256 + b * 7 + (kk - 2)] = score;
                if (score > best) { best = score; bestk = kk; }
            }
        }
        out[b] = (float)bestk;
    }
}

// ---------------------------------------------------------------------------
extern "C" void kernel_launch(void* const* d_in, const int* in_sizes, int n_in,
                              void* d_out, int out_size, void* d_ws, size_t ws_size,
                              hipStream_t stream) {
    const float* e = (const float*)d_in[0];
    const float* W = (const float*)d_in[1];
    const float* b_init = (const float*)d_in[2];
    float* out = (float*)d_out;

    float* hat = (float*)d_ws;
    float* c_final = hat + (size_t)NB * NL * NH;
    float* strength = c_final + (size_t)NB * NK * NL;

    hipLaunchKernelGGL(hat_kernel, dim3((NB * NL) / 64), dim3(256), 0, stream, e, W, hat);
    hipLaunchKernelGGL(routing_kernel, dim3(NB), dim3(1024), 0, stream, hat, b_init, c_final, strength);
    hipLaunchKernelGGL(score_kernel, dim3(NB), dim3(1024), 0, stream, e, c_final, strength, out);
}

// Round 3
// 70.398 us; speedup vs baseline: 1.8884x; 1.3139x over previous
//
#include <hip/hip_runtime.h>
#include <hip/hip_bf16.h>
#include <math.h>

#define NB 256   // batch
#define NL 256   // sequence length
#define NH 128   // hidden
#define NK 8     // K_MAX

typedef __attribute__((ext_vector_type(8))) short bf16x8;
typedef __attribute__((ext_vector_type(4))) float f32x4;
typedef __attribute__((ext_vector_type(4))) short short4v;

static __device__ __forceinline__ short f2bf(float x) {
    __hip_bfloat16 b = __float2bfloat16(x);
    return *reinterpret_cast<short*>(&b);
}
static __device__ __forceinline__ float bf2f(short s) {
    __hip_bfloat16 b = *reinterpret_cast<__hip_bfloat16*>(&s);
    return __bfloat162float(b);
}

// ---------------------------------------------------------------------------
// Kernel 1: hat = e @ W^T via split-bf16 MFMA (hi/lo decomposition, 3 MFMAs).
// M-tile = 128 rows, full N = K = 128. 256 threads = 4 waves, wave owns N=32.
// ---------------------------------------------------------------------------
#define APAD 136  // 128 + 8 bf16 pad -> 272B row stride, 16B aligned
__global__ __launch_bounds__(256) void hat_mfma_kernel(const float* __restrict__ e,
                                                       const float* __restrict__ W,
                                                       float* __restrict__ hat) {
    __shared__ short Ahi[128 * APAD];
    __shared__ short Alo[128 * APAD];
    const int t = threadIdx.x;
    const int lane = t & 63, wv = t >> 6;
    const int l16 = lane & 15, grp = lane >> 4;
    const size_t row0 = (size_t)blockIdx.x * 128;
    const int n0 = wv * 32;

    // --- preload W fragments into registers (hi/lo), 2 n-frags x 4 k-steps ---
    bf16x8 bhi[2][4], blo[2][4];
#pragma unroll
    for (int nf = 0; nf < 2; ++nf) {
#pragma unroll
        for (int ks = 0; ks < 4; ++ks) {
            const int col = n0 + nf * 16 + l16;
            const int kb = ks * 32 + grp * 8;
            const float4 w0 = *(const float4*)&W[col * 128 + kb];
            const float4 w1 = *(const float4*)&W[col * 128 + kb + 4];
            const float wx[8] = {w0.x, w0.y, w0.z, w0.w, w1.x, w1.y, w1.z, w1.w};
            bf16x8 h, l;
#pragma unroll
            for (int j = 0; j < 8; ++j) {
                const short hv = f2bf(wx[j]);
                h[j] = hv;
                l[j] = f2bf(wx[j] - bf2f(hv));
            }
            bhi[nf][ks] = h;
            blo[nf][ks] = l;
        }
    }

    // --- stage e tile as bf16 hi/lo into LDS ---
#pragma unroll
    for (int it = 0; it < 16; ++it) {
        const int idx = (it * 256 + t) * 4;     // element index in 128x128 tile
        const int r = idx >> 7, k = idx & 127;
        const float4 v = *(const float4*)&e[(row0 + r) * 128 + k];
        const float vx[4] = {v.x, v.y, v.z, v.w};
        short4v hi, lo;
#pragma unroll
        for (int j = 0; j < 4; ++j) {
            const short hv = f2bf(vx[j]);
            hi[j] = hv;
            lo[j] = f2bf(vx[j] - bf2f(hv));
        }
        *(short4v*)&Ahi[r * APAD + k] = hi;
        *(short4v*)&Alo[r * APAD + k] = lo;
    }
    __syncthreads();

    // --- MFMA main loop ---
    f32x4 acc[8][2];
#pragma unroll
    for (int mf = 0; mf < 8; ++mf)
#pragma unroll
        for (int nf = 0; nf < 2; ++nf) acc[mf][nf] = (f32x4){0.f, 0.f, 0.f, 0.f};

#pragma unroll
    for (int ks = 0; ks < 4; ++ks) {
        const int kb = ks * 32 + grp * 8;
#pragma unroll
        for (int mf = 0; mf < 8; ++mf) {
            const int arow = mf * 16 + l16;
            const bf16x8 ahi = *(const bf16x8*)&Ahi[arow * APAD + kb];
            const bf16x8 alo = *(const bf16x8*)&Alo[arow * APAD + kb];
#pragma unroll
            for (int nf = 0; nf < 2; ++nf) {
                acc[mf][nf] = __builtin_amdgcn_mfma_f32_16x16x32_bf16(ahi, bhi[nf][ks], acc[mf][nf], 0, 0, 0);
                acc[mf][nf] = __builtin_amdgcn_mfma_f32_16x16x32_bf16(alo, bhi[nf][ks], acc[mf][nf], 0, 0, 0);
                acc[mf][nf] = __builtin_amdgcn_mfma_f32_16x16x32_bf16(ahi, blo[nf][ks], acc[mf][nf], 0, 0, 0);
            }
        }
    }

    // --- write C: col = lane&15, row = grp*4 + reg ---
#pragma unroll
    for (int mf = 0; mf < 8; ++mf)
#pragma unroll
        for (int nf = 0; nf < 2; ++nf)
#pragma unroll
            for (int r = 0; r < 4; ++r)
                hat[(row0 + mf * 16 + grp * 4 + r) * 128 + n0 + nf * 16 + l16] = acc[mf][nf][r];
}

// ---------------------------------------------------------------------------
// Kernel 2: dynamic routing. One block per batch, 1024 threads (16 waves).
// ---------------------------------------------------------------------------
__global__ __launch_bounds__(1024) void routing_kernel(const float* __restrict__ hat,
                                                       const float* __restrict__ b_init,
                                                       float* __restrict__ c_out,
                                                       float* __restrict__ str_out) {
    const int b = blockIdx.x;
    const int t = threadIdx.x;
    const int lane = t & 63, wv = t >> 6;
    __shared__ float logits[NK * NL];
    __shared__ __align__(16) float ct[NL * 12];
    __shared__ __align__(16) float cap[NK * NH];
    __shared__ __align__(16) float red[8192];
    __shared__ __align__(16) float tile[64 * 129];
    __shared__ float nrm[NK];
    const float* hatb = hat + (size_t)b * (NL * NH);

    logits[t] = b_init[(size_t)b * 2048 + t];
    logits[t + 1024] = b_init[(size_t)b * 2048 + t + 1024];
    __syncthreads();

    const int h = t & 127, lgrp = t >> 7;

    for (int iter = 0; iter < 3; ++iter) {
        if (wv < 8) {
            const int k = wv;
            float v0 = logits[k * 256 + lane];
            float v1 = logits[k * 256 + 64 + lane];
            float v2 = logits[k * 256 + 128 + lane];
            float v3 = logits[k * 256 + 192 + lane];
            float m = fmaxf(fmaxf(v0, v1), fmaxf(v2, v3));
            for (int o = 32; o; o >>= 1) m = fmaxf(m, __shfl_xor(m, o));
            v0 = expf(v0 - m); v1 = expf(v1 - m); v2 = expf(v2 - m); v3 = expf(v3 - m);
            float s = v0 + v1 + v2 + v3;
            for (int o = 32; o; o >>= 1) s += __shfl_xor(s, o);
            const float inv = 1.0f / s;
            ct[lane * 12 + k] = v0 * inv;
            ct[(lane + 64) * 12 + k] = v1 * inv;
            ct[(lane + 128) * 12 + k] = v2 * inv;
            ct[(lane + 192) * 12 + k] = v3 * inv;
        }
        __syncthreads();

        float acc[8] = {0, 0, 0, 0, 0, 0, 0, 0};
        {
            const int l0g = lgrp * 32;
#pragma unroll 4
            for (int li = 0; li < 32; ++li) {
                const int l = l0g + li;
                const float ev = hatb[l * 128 + h];
                const float4 c0 = *(const float4*)&ct[l * 12];
                const float4 c1 = *(const float4*)&ct[l * 12 + 4];
                acc[0] += c0.x * ev; acc[1] += c0.y * ev; acc[2] += c0.z * ev; acc[3] += c0.w * ev;
                acc[4] += c1.x * ev; acc[5] += c1.y * ev; acc[6] += c1.z * ev; acc[7] += c1.w * ev;
            }
        }
#pragma unroll
        for (int k = 0; k < 8; ++k) red[lgrp * 1024 + k * 128 + h] = acc[k];
        __syncthreads();
        {
            float cv = 0.f;
#pragma unroll
            for (int g = 0; g < 8; ++g) cv += red[g * 1024 + t];
            cap[t] = cv;
        }
        __syncthreads();
        if (wv < 8) {
            const int k = wv;
            float x0 = cap[k * 128 + lane], x1 = cap[k * 128 + 64 + lane];
            float s = x0 * x0 + x1 * x1;
            for (int o = 32; o; o >>= 1) s += __shfl_xor(s, o);
            if (lane == 0) nrm[k] = s;
        }
        __syncthreads();
        {
            const float n = nrm[t >> 7];
            cap[t] = cap[t] * (n / (1.0f + n) / sqrtf(n + 1e-9f));
        }
        __syncthreads();

        if (iter < 2) {
            for (int l0 = 0; l0 < 256; l0 += 64) {
#pragma unroll
                for (int rep = 0; rep < 2; ++rep) {
                    const int i2 = t + rep * 1024;
                    const int r = i2 >> 5, c0 = (i2 & 31) * 4;
                    const float4 v = *(const float4*)&hatb[(size_t)(l0 + r) * 128 + c0];
                    tile[r * 129 + c0 + 0] = v.x;
                    tile[r * 129 + c0 + 1] = v.y;
                    tile[r * 129 + c0 + 2] = v.z;
                    tile[r * 129 + c0 + 3] = v.w;
                }
                __syncthreads();
                const int h0 = wv * 8;
                float cr[8][8];
#pragma unroll
                for (int k = 0; k < 8; ++k) {
                    const float4 a = *(const float4*)&cap[k * 128 + h0];
                    const float4 bq = *(const float4*)&cap[k * 128 + h0 + 4];
                    cr[k][0] = a.x; cr[k][1] = a.y; cr[k][2] = a.z; cr[k][3] = a.w;
                    cr[k][4] = bq.x; cr[k][5] = bq.y; cr[k][6] = bq.z; cr[k][7] = bq.w;
                }
                float p[8] = {0, 0, 0, 0, 0, 0, 0, 0};
#pragma unroll
                for (int u = 0; u < 8; ++u) {
                    const float v = tile[lane * 129 + h0 + u];
#pragma unroll
                    for (int k = 0; k < 8; ++k) p[k] += v * cr[k][u];
                }
#pragma unroll
                for (int k = 0; k < 8; ++k) red[wv * 512 + k * 64 + lane] = p[k];
                __syncthreads();
                if (t < 512) {
                    float d = 0.f;
#pragma unroll
                    for (int q = 0; q < 16; ++q) d += red[q * 512 + t];
                    logits[(t >> 6) * 256 + l0 + (t & 63)] += d;
                }
                __syncthreads();
            }
        }
    }

    if (wv < 8) {
        const int k = wv;
        float x0 = cap[k * 128 + lane], x1 = cap[k * 128 + 64 + lane];
        float s = x0 * x0 + x1 * x1;
        for (int o = 32; o; o >>= 1) s += __shfl_xor(s, o);
        if (lane == 0) str_out[b * 8 + k] = sqrtf(s);
    }
#pragma unroll
    for (int rep = 0; rep < 2; ++rep) {
        const int i = t + rep * 1024;
        c_out[(size_t)b * 2048 + i] = ct[(i & 255) * 12 + (i >> 8)];
    }
}

// ---------------------------------------------------------------------------
// Kernel 3: per-batch scoring, 1024 threads.
// ---------------------------------------------------------------------------
__global__ __launch_bounds__(1024) void score_kernel(const float* __restrict__ e_in,
                                                     const float* __restrict__ c_in,
                                                     const float* __restrict__ str_in,
                                                     float* __restrict__ out) {
    const int b = blockIdx.x;
    const int t = threadIdx.x;
    const int lane = t & 63, wv = t >> 6;
    __shared__ __align__(16) float ct[NL * 12];
    __shared__ __align__(16) float tile[64 * 129];
    __shared__ __align__(16) float mu[NK * NH];
    __shared__ __align__(16) float red[16 * 576];
    __shared__ float enl[64];
    __shared__ float denom[NK], nrmv[NK], svals[NK], Ps[28], str[NK];
    const float* eb = e_in + (size_t)b * (NL * NH);

#pragma unroll
    for (int rep = 0; rep < 2; ++rep) {
        const int i = t + rep * 1024;
        ct[(i & 255) * 12 + (i >> 8)] = c_in[(size_t)b * 2048 + i];
    }
    if (t < 8) str[t] = str_in[b * 8 + t];
    __syncthreads();

    if (wv < 8) {
        const int k = wv;
        float s = ct[lane * 12 + k] + ct[(lane + 64) * 12 + k] +
                  ct[(lane + 128) * 12 + k] + ct[(lane + 192) * 12 + k];
        for (int o = 32; o; o >>= 1) s += __shfl_xor(s, o);
        if (lane == 0) denom[k] = s + 1e-8f;
    }
    __syncthreads();

    const int h = t & 127, lgrp = t >> 7;

    {
        float acc[8] = {0, 0, 0, 0, 0, 0, 0, 0};
        const int l0g = lgrp * 32;
#pragma unroll 4
        for (int li = 0; li < 32; ++li) {
            const int l = l0g + li;
            const float ev = eb[l * 128 + h];
            const float4 c0 = *(const float4*)&ct[l * 12];
            const float4 c1 = *(const float4*)&ct[l * 12 + 4];
            acc[0] += c0.x * ev; acc[1] += c0.y * ev; acc[2] += c0.z * ev; acc[3] += c0.w * ev;
            acc[4] += c1.x * ev; acc[5] += c1.y * ev; acc[6] += c1.z * ev; acc[7] += c1.w * ev;
        }
#pragma unroll
        for (int k = 0; k < 8; ++k) red[lgrp * 1024 + k * 128 + h] = acc[k];
    }
    __syncthreads();
    {
        float cv = 0.f;
#pragma unroll
        for (int g = 0; g < 8; ++g) cv += red[g * 1024 + t];
        mu[t] = cv / denom[t >> 7];
    }
    __syncthreads();
    if (wv < 8) {
        const int k = wv;
        float x0 = mu[k * 128 + lane], x1 = mu[k * 128 + 64 + lane];
        float s = x0 * x0 + x1 * x1;
        for (int o = 32; o; o >>= 1) s += __shfl_xor(s, o);
        if (lane == 0) nrmv[k] = sqrtf(s) + 1e-8f;
    }
    __syncthreads();
    mu[t] /= nrmv[t >> 7];
    __syncthreads();

    float mr[8][8];
    {
        const int h0 = wv * 8;
#pragma unroll
        for (int k = 0; k < 8; ++k) {
            const float4 a = *(const float4*)&mu[k * 128 + h0];
            const float4 bq = *(const float4*)&mu[k * 128 + h0 + 4];
            mr[k][0] = a.x; mr[k][1] = a.y; mr[k][2] = a.z; mr[k][3] = a.w;
            mr[k][4] = bq.x; mr[k][5] = bq.y; mr[k][6] = bq.z; mr[k][7] = bq.w;
        }
    }
    float sacc = 0.f;
    for (int l0 = 0; l0 < 256; l0 += 64) {
#pragma unroll
        for (int rep = 0; rep < 2; ++rep) {
            const int i2 = t + rep * 1024;
            const int r = i2 >> 5, c0 = (i2 & 31) * 4;
            const float4 v = *(const float4*)&eb[(size_t)(l0 + r) * 128 + c0];
            tile[r * 129 + c0 + 0] = v.x;
            tile[r * 129 + c0 + 1] = v.y;
            tile[r * 129 + c0 + 2] = v.z;
            tile[r * 129 + c0 + 3] = v.w;
        }
        __syncthreads();
        {
            const int h0 = wv * 8;
            float en2 = 0.f;
            float p[8] = {0, 0, 0, 0, 0, 0, 0, 0};
#pragma unroll
            for (int u = 0; u < 8; ++u) {
                const float v = tile[lane * 129 + h0 + u];
                en2 += v * v;
#pragma unroll
                for (int k = 0; k < 8; ++k) p[k] += v * mr[k][u];
            }
#pragma unroll
            for (int k = 0; k < 8; ++k) red[wv * 576 + k * 64 + lane] = p[k];
            red[wv * 576 + 512 + lane] = en2;
        }
        __syncthreads();
        if (t < 64) {
            float s2 = 0.f;
#pragma unroll
            for (int q = 0; q < 16; ++q) s2 += red[q * 576 + 512 + t];
            enl[t] = sqrtf(s2) + 1e-8f;
        }
        __syncthreads();
        if (t < 512) {
            const int k = t >> 6, l = t & 63;
            float d = 0.f;
#pragma unroll
            for (int q = 0; q < 16; ++q) d += red[q * 576 + t];
            float val = ct[(l0 + l) * 12 + k] * (d / enl[l]);
            for (int o = 32; o; o >>= 1) val += __shfl_xor(val, o);
            sacc += val;
        }
        __syncthreads();
    }
    if (wv < 8 && lane == 0) svals[wv] = sacc;
    __syncthreads();

    for (int p = wv; p < 28; p += 16) {
        int i = 0, rem = p;
        while (rem >= 7 - i) { rem -= 7 - i; ++i; }
        const int j = i + 1 + rem;
        float v = mu[i * 128 + lane] * mu[j * 128 + lane] +
                  mu[i * 128 + 64 + lane] * mu[j * 128 + 64 + lane];
        for (int o = 32; o; o >>= 1) v += __shfl_xor(v, o);
        if (lane == 0) Ps[p] = v;
    }
    __syncthreads();

    if (t == 0) {
        int idx[8];
        for (int i = 0; i < 8; ++i) idx[i] = i;
        for (int a = 1; a < 8; ++a) {
            const int key = idx[a];
            const float kv = str[key];
            int bb = a - 1;
            while (bb >= 0 && str[idx[bb]] < kv) { idx[bb + 1] = idx[bb]; --bb; }
            idx[bb + 1] = key;
        }
        float best = -1e30f;
        int bestk = 2;
        float cons_sum = 0.f, pair_sum = 0.f;
        for (int kk = 1; kk <= 8; ++kk) {
            const int ni = idx[kk - 1];
            cons_sum += svals[ni];
            for (int a = 0; a < kk - 1; ++a) {
                const int ia = idx[a];
                const int lo = ia < ni ? ia : ni;
                const int hi2 = ia < ni ? ni : ia;
                const int off0 = lo * 7 - lo * (lo - 1) / 2;
                pair_sum += Ps[off0 + hi2 - lo - 1];
            }
            if (kk >= 2) {
                const float cons = cons_sum / (kk * 256.0f);
                const float divv = 1.0f - (2.0f / (kk * (kk - 1))) * pair_sum;
                const float score = 0.5f * cons + 0.5f * divv;
                out[256 + b * 7 + (kk - 2)] = score;
                if (score > best) { best = score; bestk = kk; }
            }
        }
        out[b] = (float)bestk;
    }
}

// ---------------------------------------------------------------------------
extern "C" void kernel_launch(void* const* d_in, const int* in_sizes, int n_in,
                              void* d_out, int out_size, void* d_ws, size_t ws_size,
                              hipStream_t stream) {
    const float* e = (const float*)d_in[0];
    const float* W = (const float*)d_in[1];
    const float* b_init = (const float*)d_in[2];
    float* out = (float*)d_out;

    float* hat = (float*)d_ws;
    float* c_final = hat + (size_t)NB * NL * NH;
    float* strength = c_final + (size_t)NB * NK * NL;

    hipLaunchKernelGGL(hat_mfma_kernel, dim3((NB * NL) / 128), dim3(256), 0, stream, e, W, hat);
    hipLaunchKernelGGL(routing_kernel, dim3(NB), dim3(1024), 0, stream, hat, b_init, c_final, strength);
    hipLaunchKernelGGL(score_kernel, dim3(NB), dim3(1024), 0, stream, e, c_final, strength, out);
}